// Round 7
// baseline (246.443 us; speedup 1.0000x reference)
//
#include <hip/hip_runtime.h>

// PointGatedBlock: SE3 point conv + gated nonlinearity. fp32 in/out.
// R7: BARRIER-FREE m-loop. Each lane computes its own MFMA A-frag (phi) in
// registers (k = l15 fixed per lane; m = q*8+j); B-frags (feat, bf16,
// L2-resident) loaded per-MFMA from pre-converted ws. No LDS / no
// __syncthreads in the m-loop -> no convoying, HBM latency hidden by
// half-iter register prefetch + 16 waves/CU TLP.
// grid 512 = (b, 8-n); block 512 (8 waves, 1 rowtile each). LDS only for the
// Tt/y tail (32 KB -> LDS no longer the occupancy limiter).
//  GEMM1: per wave: rowtile n=wave (rows = k 0..15), 7 coltiles (i 0..111,
//         rows 104..111 zeroed by lane-select). acc 7 x f32x4.
//  GEMM2: y[144 o][8 n] = W . Tt  (unchanged from R6)
//  epilogue: relu / y*sigmoid(gate), fp32 out.

typedef __attribute__((ext_vector_type(4))) float f32x4;
typedef __attribute__((ext_vector_type(8))) short s16x8;
typedef __attribute__((ext_vector_type(4))) unsigned int u32x4;

#define DI 104
#define DO 144
#define TTST 1688          // Tt row stride (elems): 844 dwords -> 12-bank row skew
#define YST 9

#define W_ELEMS 239616     // 16*144*104
#define F_ELEMS 425984     // 4*104*1024

#define OFF_Y 27008                      // 8*TTST*2
#define SMEM_TOTAL (27008 + 144*9*4)     // 32192 B

__device__ __forceinline__ float fexp2(float x) {
#if __has_builtin(__builtin_amdgcn_exp2f)
    return __builtin_amdgcn_exp2f(x);
#else
    return exp2f(x);
#endif
}
__device__ __forceinline__ float fsqrt_(float x) {
#if __has_builtin(__builtin_amdgcn_sqrtf)
    return __builtin_amdgcn_sqrtf(x);
#else
    return sqrtf(x);
#endif
}
__device__ __forceinline__ float frcp_(float x) {
#if __has_builtin(__builtin_amdgcn_rcpf)
    return __builtin_amdgcn_rcpf(x);
#else
    return 1.0f / x;
#endif
}
__device__ __forceinline__ unsigned int pkbf(float lo, float hi) {
    unsigned int a = __builtin_bit_cast(unsigned int, lo) + 0x8000u;
    unsigned int b = __builtin_bit_cast(unsigned int, hi) + 0x8000u;
    return __builtin_amdgcn_perm(b, a, 0x07060302u);
}
__device__ __forceinline__ unsigned short f2b(float f) {
    return (unsigned short)((__builtin_bit_cast(unsigned int, f) + 0x8000u) >> 16);
}

// ---- pre-kernel: fp32 -> bf16 for W (ws[0..W_ELEMS)) and feat (ws[W_ELEMS..)) ----
__global__ __launch_bounds__(256, 8)
void cvt_kernel(const float* __restrict__ feat_g, const float* __restrict__ W_g,
                unsigned short* __restrict__ ws)
{
    int gid = blockIdx.x * 256 + threadIdx.x;           // 8 elems per thread
    const float* src;
    unsigned short* dst;
    if (gid < W_ELEMS/8) {
        src = W_g + gid*8;  dst = ws + gid*8;
    } else {
        int g2 = gid - W_ELEMS/8;
        src = feat_g + g2*8; dst = ws + W_ELEMS + g2*8;
    }
    f32x4 a = *(const f32x4*)src;
    f32x4 b = *(const f32x4*)(src + 4);
    unsigned int o[4] = { pkbf(a[0],a[1]), pkbf(a[2],a[3]), pkbf(b[0],b[1]), pkbf(b[2],b[3]) };
    *(f32x4*)dst = *(f32x4*)o;
}

__global__ __launch_bounds__(512, 4)
void pgb_kernel(const unsigned short* __restrict__ ws,   // Wbf | featbf
                const float* __restrict__ diff_g,
                const float* __restrict__ mask_g,
                float* __restrict__ out_g)
{
    const unsigned short* Wbf    = ws;
    const unsigned short* featbf = ws + W_ELEMS;

    __shared__ __align__(16) unsigned char smem[SMEM_TOTAL];
    unsigned short* Tt   = (unsigned short*)smem;
    float*          ylds = (float*)(smem + OFF_Y);

    const int t    = threadIdx.x;
    const int b    = blockIdx.x >> 7;
    const int n0   = (blockIdx.x & 127) << 3;
    const int wave = t >> 6;
    const int lane = t & 63;
    const int l15  = lane & 15;
    const int q    = lane >> 4;
    const int mq   = q << 3;

    // per-lane radial-basis constants for k = l15:
    // e = CEXP*(r-ck)^2 = fma(r, fma(CEXP, r, B1k), B0k)
    const float CEXP = -23.083120654223414f;   // -GAMMA * log2(e)
    const float ck   = (float)l15 * (2.0f/15.0f);
    const float B1k  = -2.0f * CEXP * ck;
    const float B0k  = CEXP * ck * ck;

    const size_t drow  = ((size_t)((b << 10) + n0 + wave)) << 10;  // this wave's n-row
    const size_t fbase = ((size_t)b * DI) << 10;

    f32x4 acc[7];
#pragma unroll
    for (int cc = 0; cc < 7; ++cc) acc[cc] = (f32x4){0.f, 0.f, 0.f, 0.f};

    f32x4 D0[6], D1[6], M0[2], M1[2];

    auto loadDM = [&](f32x4* D, f32x4* M, int m0) {
        const float* dp = diff_g + (drow + m0)*3;
#pragma unroll
        for (int u = 0; u < 6; ++u) D[u] = *(const f32x4*)(dp + 4*u);
        const float* mp = mask_g + drow + m0;
        M[0] = *(const f32x4*)mp;
        M[1] = *(const f32x4*)(mp + 4);
    };

    auto halfstep = [&](const f32x4* D, const f32x4* M, int m0) {
        // B-frags straight from L2-resident bf16 feat
        s16x8 bfr[7];
#pragma unroll
        for (int cc = 0; cc < 6; ++cc) {
            int i = cc*16 + l15;
            bfr[cc] = *(const s16x8*)(featbf + fbase + ((size_t)i << 10) + m0);
        }
        bfr[6] = *(const s16x8*)(featbf + fbase + ((size_t)(96 + (l15 & 7)) << 10) + m0);
        if (l15 >= 8) bfr[6] = (s16x8){0,0,0,0,0,0,0,0};
        // phi -> A-frag (8 elements, all in registers)
        float p[8];
#pragma unroll
        for (int j = 0; j < 8; ++j) {
            float dx = D[(3*j+0) >> 2][(3*j+0) & 3];
            float dy = D[(3*j+1) >> 2][(3*j+1) & 3];
            float dz = D[(3*j+2) >> 2][(3*j+2) & 3];
            float r  = fsqrt_(fmaf(dx, dx, fmaf(dy, dy, fmaf(dz, dz, 1e-12f))));
            float e  = fmaf(r, fmaf(CEXP, r, B1k), B0k);
            p[j] = fexp2(e) * M[j >> 2][j & 3];
        }
        u32x4 pk;
        pk[0] = pkbf(p[0], p[1]); pk[1] = pkbf(p[2], p[3]);
        pk[2] = pkbf(p[4], p[5]); pk[3] = pkbf(p[6], p[7]);
        s16x8 af = __builtin_bit_cast(s16x8, pk);
#pragma unroll
        for (int cc = 0; cc < 7; ++cc)
            acc[cc] = __builtin_amdgcn_mfma_f32_16x16x32_bf16(af, bfr[cc], acc[cc], 0, 0, 0);
    };

    // ---- barrier-free m-loop: 16 iters x 2 half-iters of 32 m ----
    loadDM(D0, M0, mq);                      // (s=0, kk=0)
    for (int s = 0; s < 16; ++s) {
        const int m00 = s*64 + mq;
        loadDM(D1, M1, m00 + 32);            // prefetch (s, kk=1)
        halfstep(D0, M0, m00);
        if (s < 15) loadDM(D0, M0, m00 + 64);// prefetch (s+1, kk=0)
        halfstep(D1, M1, m00 + 32);
    }

    // ---- acc (C: col=l15=i_local, row=q*4+r=k) -> Tt[n=wave][k*104+i] bf16 ----
#pragma unroll
    for (int cc = 0; cc < 7; ++cc) {
        int i = cc*16 + l15;
        if (cc < 6 || l15 < 8) {
#pragma unroll
            for (int r = 0; r < 4; ++r)
                Tt[wave*TTST + (q*4 + r)*DI + i] = f2b(acc[cc][r]);
        }
    }
    __syncthreads();

    // ---- GEMM2: y[o,n] = sum_ki Wbf[k,o,i]*Tt[n][ki]; 52 K-steps of 32 ----
    // B-cols 8..15 duplicate rows 0..7 (broadcast) and are ignored at write.
    f32x4 y0 = (f32x4){0.f,0.f,0.f,0.f}, y1 = (f32x4){0.f,0.f,0.f,0.f};
    const int o0 = wave*16 + l15;
    const int o1 = 128 + l15;            // o-tile 8, wave 0's second acc
#pragma unroll 4
    for (int s3 = 0; s3 < 52; ++s3) {
        int a = s3*4 + q;                // 8-elem ki block; k=a/13, i=(a%13)*8
        int k = a / 13;
        int i = (a - k*13) << 3;
        s16x8 bf = *(const s16x8*)(Tt + (l15 & 7)*TTST + s3*32 + q*8);
        s16x8 af = *(const s16x8*)(Wbf + (size_t)(k*DO + o0)*DI + i);
        y0 = __builtin_amdgcn_mfma_f32_16x16x32_bf16(af, bf, y0, 0, 0, 0);
        if (wave == 0) {
            s16x8 ag = *(const s16x8*)(Wbf + (size_t)(k*DO + o1)*DI + i);
            y1 = __builtin_amdgcn_mfma_f32_16x16x32_bf16(ag, bf, y1, 0, 0, 0);
        }
    }
    if (l15 < 8) {
#pragma unroll
        for (int r = 0; r < 4; ++r)
            ylds[(wave*16 + q*4 + r)*YST + l15] = y0[r];
        if (wave == 0) {
#pragma unroll
            for (int r = 0; r < 4; ++r)
                ylds[(128 + q*4 + r)*YST + l15] = y1[r];
        }
    }
    __syncthreads();

    // ---- gating epilogue: out[b, o(<120), n0+nn] fp32 ----
    const float L2E = 1.4426950408889634f;
    for (int idx = t; idx < 120*8; idx += 512) {
        int o = idx >> 3, nn = idx & 7;
        float y = ylds[o*YST + nn];
        float v;
        if (o < 32) {
            v = fmaxf(y, 0.f);
        } else if (o < 80) {
            float g = ylds[(120 + (o-32)/3)*YST + nn];
            v = y * frcp_(1.f + fexp2(-g*L2E));
        } else {
            float g = ylds[(136 + (o-80)/5)*YST + nn];
            v = y * frcp_(1.f + fexp2(-g*L2E));
        }
        out_g[((size_t)(b*120 + o) << 10) + n0 + nn] = v;
    }
}

extern "C" void kernel_launch(void* const* d_in, const int* in_sizes, int n_in,
                              void* d_out, int out_size, void* d_ws, size_t ws_size,
                              hipStream_t stream) {
    const float* feat = (const float*)d_in[0];  // [4,104,1024] fp32
    const float* diff = (const float*)d_in[1];  // [4,1024,1024,3] fp32
    const float* mask = (const float*)d_in[2];  // [4,1024,1024] fp32
    const float* W    = (const float*)d_in[3];  // [16,144,104] fp32
    float* out = (float*)d_out;                 // [4,120,1024] fp32
    unsigned short* ws = (unsigned short*)d_ws; // Wbf (479 KB) + featbf (852 KB)
    (void)in_sizes; (void)n_in; (void)out_size; (void)ws_size;
    cvt_kernel<<<dim3((W_ELEMS + F_ELEMS)/8/256), dim3(256), 0, stream>>>(feat, W, ws);
    pgb_kernel<<<dim3(512), dim3(512), 0, stream>>>(ws, diff, mask, out);
}

// Round 9
// 141.454 us; speedup vs baseline: 1.7422x; 1.7422x over previous
//
#include <hip/hip_runtime.h>

// PointGatedBlock: SE3 point conv + gated nonlinearity. fp32 in/out.
// R9 = R8 with the feat register off-by-one fixed: single-barrier fused-phase
// m-loop. Per iter: barrier -> phi(s+1) in regs -> WRITE phi/feat(s+1) to the
// other LDS buffer (regs still hold tile s+1!) -> reload regs for s+2
// (consumed next iter after the next barrier => full-region latency cover)
// -> GEMM1(s) from LDS. exp2-VALU, ds_read/write and MFMA co-schedule in one
// region between barriers. Pre-kernel converts W+feat to bf16 in d_ws.
// grid 512 = (b, 8-n); block 512; LDS 66.6KB -> 2 blocks/CU; XOR-swizzled rows.

typedef __attribute__((ext_vector_type(4))) float f32x4;
typedef __attribute__((ext_vector_type(8))) short s16x8;

#define DI 104
#define DO 144
#define TTST 1688          // Tt row stride (elems)
#define YST 9

#define W_ELEMS 239616     // 16*144*104
#define F_ELEMS 425984     // 4*104*1024

// LDS byte offsets (phi/feat rows: 64 elems = 128 B, XOR-swizzled blocks)
#define OFF_PHI0 0
#define OFF_PHI1 16384                  // 128*64*2
#define OFF_FEAT0 32768
#define OFF_FEAT1 47104                 // + 112*64*2 = 14336
#define OFF_Y 61440
#define SMEM_TOTAL (61440 + 144*9*4)    // 66624 B -> 2 blocks/CU

__device__ __forceinline__ float fexp2(float x) {
#if __has_builtin(__builtin_amdgcn_exp2f)
    return __builtin_amdgcn_exp2f(x);
#else
    return exp2f(x);
#endif
}
__device__ __forceinline__ float flog2(float x) {
#if __has_builtin(__builtin_amdgcn_logf)
    return __builtin_amdgcn_logf(x);
#else
    return log2f(x);
#endif
}
__device__ __forceinline__ float fsqrt_(float x) {
#if __has_builtin(__builtin_amdgcn_sqrtf)
    return __builtin_amdgcn_sqrtf(x);
#else
    return sqrtf(x);
#endif
}
__device__ __forceinline__ float frcp_(float x) {
#if __has_builtin(__builtin_amdgcn_rcpf)
    return __builtin_amdgcn_rcpf(x);
#else
    return 1.0f / x;
#endif
}
__device__ __forceinline__ unsigned int pkbf(float lo, float hi) {
    unsigned int a = __builtin_bit_cast(unsigned int, lo) + 0x8000u;
    unsigned int b = __builtin_bit_cast(unsigned int, hi) + 0x8000u;
    return __builtin_amdgcn_perm(b, a, 0x07060302u);
}
__device__ __forceinline__ unsigned short f2b(float f) {
    return (unsigned short)((__builtin_bit_cast(unsigned int, f) + 0x8000u) >> 16);
}

// ---- pre-kernel: fp32 -> bf16 for W (ws[0..W_ELEMS)) and feat (ws[W_ELEMS..)) ----
__global__ __launch_bounds__(256, 8)
void cvt_kernel(const float* __restrict__ feat_g, const float* __restrict__ W_g,
                unsigned short* __restrict__ ws)
{
    int gid = blockIdx.x * 256 + threadIdx.x;           // 8 elems per thread
    const float* src;
    unsigned short* dst;
    if (gid < W_ELEMS/8) {
        src = W_g + gid*8;  dst = ws + gid*8;
    } else {
        int g2 = gid - W_ELEMS/8;
        src = feat_g + g2*8; dst = ws + W_ELEMS + g2*8;
    }
    f32x4 a = *(const f32x4*)src;
    f32x4 b = *(const f32x4*)(src + 4);
    unsigned int o[4] = { pkbf(a[0],a[1]), pkbf(a[2],a[3]), pkbf(b[0],b[1]), pkbf(b[2],b[3]) };
    *(f32x4*)dst = *(f32x4*)o;
}

// load-tile macro: diff/mask regs for this thread's (n-row, 2 m cols) at m-base M0
#define LOAD_DM(M0)                                                    \
    do {                                                               \
        const float* dp_ = diff_g + (dmrow + (M0) + pml)*3;            \
        dx0 = dp_[0]; dy0 = dp_[1]; dz0 = dp_[2];                      \
        dx1 = dp_[3]; dy1 = dp_[4]; dz1 = dp_[5];                      \
        const float* mp_ = mask_g + dmrow + (M0) + pml;                \
        mk0 = mp_[0]; mk1 = mp_[1];                                    \
    } while (0)

#define LOAD_FEAT(M0)                                                          \
    do {                                                                       \
        fr0 = *(const s16x8*)(featbf + fbase + ((size_t)fi0 << 10) + (M0) + (fj << 3)); \
        if (t < 320)                                                           \
            fr1 = *(const s16x8*)(featbf + fbase + ((size_t)fi1 << 10) + (M0) + (fj << 3)); \
    } while (0)

// phi from current dx../mk regs -> pk[0..7] (packed bf16x2 per k-row j)
#define COMPUTE_PHI()                                                  \
    do {                                                               \
        float r0_ = fsqrt_(fmaf(dx0,dx0, fmaf(dy0,dy0, fmaf(dz0,dz0, 1e-12f)))); \
        float r1_ = fsqrt_(fmaf(dx1,dx1, fmaf(dy1,dy1, fmaf(dz1,dz1, 1e-12f)))); \
        float t0_ = r0_ - K0OFF, t1_ = r1_ - K0OFF;                    \
        float E0_ = fmaf(CEXP*t0_, t0_, flog2(mk0));                   \
        float E1_ = fmaf(CEXP*t1_, t1_, flog2(mk1));                   \
        float s0_ = fmaf(A1, r0_, S0B);                                \
        float s1_ = fmaf(A1, r1_, S0B);                                \
        _Pragma("unroll")                                              \
        for (int j_ = 0; j_ < 8; ++j_) {                               \
            pk[j_] = pkbf(fexp2(E0_), fexp2(E1_));                     \
            E0_ += s0_; s0_ += V2;                                     \
            E1_ += s1_; s1_ += V2;                                     \
        }                                                              \
    } while (0)

#define WRITE_PHI(BUF)                                                 \
    do {                                                               \
        unsigned short* pw_ = (BUF) + (pn*16 + kh*8)*64 + pin;         \
        _Pragma("unroll")                                              \
        for (int j_ = 0; j_ < 8; ++j_)                                 \
            *(unsigned int*)(pw_ + j_*64 + ((pblk ^ j_) << 3)) = pk[j_]; \
    } while (0)

#define WRITE_FEAT(BUF)                                                \
    do {                                                               \
        *(s16x8*)((BUF) + fi0*64 + fjs) = fr0;                         \
        if (t < 320) *(s16x8*)((BUF) + fi1*64 + fjs) = fr1;            \
    } while (0)

#define GEMM1(PBUF, FBUF)                                              \
    do {                                                               \
        _Pragma("unroll")                                              \
        for (int kk_ = 0; kk_ < 2; ++kk_) {                            \
            const int mo_ = ((kk_*4 + q) ^ sw) << 3;                   \
            s16x8 a0_ = *(const s16x8*)((PBUF) + ((2*wr    )*16 + l15)*64 + mo_); \
            s16x8 a1_ = *(const s16x8*)((PBUF) + ((2*wr + 1)*16 + l15)*64 + mo_); \
            _Pragma("unroll")                                          \
            for (int cc_ = 0; cc_ < 4; ++cc_) {                        \
                if (ct0 + cc_ < 7) {                                   \
                    s16x8 bf_ = *(const s16x8*)((FBUF) + ((ct0+cc_)*16 + l15)*64 + mo_); \
                    acc[0][cc_] = __builtin_amdgcn_mfma_f32_16x16x32_bf16(a0_, bf_, acc[0][cc_], 0, 0, 0); \
                    acc[1][cc_] = __builtin_amdgcn_mfma_f32_16x16x32_bf16(a1_, bf_, acc[1][cc_], 0, 0, 0); \
                }                                                      \
            }                                                          \
        }                                                              \
    } while (0)

__global__ __launch_bounds__(512, 4)
void pgb_kernel(const unsigned short* __restrict__ ws,   // Wbf | featbf
                const float* __restrict__ diff_g,
                const float* __restrict__ mask_g,
                float* __restrict__ out_g)
{
    const unsigned short* Wbf    = ws;
    const unsigned short* featbf = ws + W_ELEMS;

    __shared__ __align__(16) unsigned char smem[SMEM_TOTAL];
    unsigned short* Tt   = (unsigned short*)smem;        // aliases phi bufs (post-barrier)
    float*          ylds = (float*)(smem + OFF_Y);
    unsigned short* phi0b  = (unsigned short*)(smem + OFF_PHI0);
    unsigned short* phi1b  = (unsigned short*)(smem + OFF_PHI1);
    unsigned short* feat0b = (unsigned short*)(smem + OFF_FEAT0);
    unsigned short* feat1b = (unsigned short*)(smem + OFF_FEAT1);

    const int t    = threadIdx.x;
    const int b    = blockIdx.x >> 7;
    const int n0   = (blockIdx.x & 127) << 3;
    const int wave = t >> 6;
    const int lane = t & 63;
    const int l15  = lane & 15;
    const int q    = lane >> 4;
    const int wr   = wave >> 1;          // rowgroup: rowtiles 2wr, 2wr+1 (n_local)
    const int ct0  = (wave & 1) << 2;    // colgroup: coltiles ct0..ct0+3 (skip 7)
    const int sw   = l15 & 7;            // read-side swizzle key (row&7)

    // zero feat pad rows 104..111 in both buffers
    if (t < 256) {
        ((unsigned int*)(smem + OFF_FEAT0 + DI*128))[t] = 0u;
        ((unsigned int*)(smem + OFF_FEAT1 + DI*128))[t] = 0u;
    }

    f32x4 acc[2][4];
#pragma unroll
    for (int rr = 0; rr < 2; ++rr)
#pragma unroll
        for (int cc = 0; cc < 4; ++cc)
            acc[rr][cc] = (f32x4){0.f, 0.f, 0.f, 0.f};

    // phi thread mapping: 8 n x 2 k-halves x 32 m-pairs
    const int pn   = t >> 6;             // n-row 0..7 (== wave)
    const int kh   = (t >> 5) & 1;       // k-half: k0 = 8*kh
    const int pml  = (t & 31) << 1;      // m pair (even), 0..62
    const int pblk = (t & 31) >> 2;      // m block 0..7 (write-side swizzle base)
    const int pin  = pml & 7;            // within-block offset
    const float CEXP = -23.083120654223414f;   // -GAMMA * log2(e)
    const float A1   = 6.155498841126244f;     // -2*CEXP*DL
    const float V2   = -0.8207331788168325f;   // 2*CEXP*DL^2
    const float K0OFF = kh ? 1.0666666666666667f : 0.f;
    const float S0B   = kh ? -6.976232019943076f : -0.41036658940841624f;
    const size_t dmrow = (size_t)((b << 10) + n0 + pn) << 10;

    // feat staging mapping
    const int fi0 = t >> 3, fj = t & 7;
    const int fi1 = 64 + (t >> 3);
    const int fjs = (fj ^ (fi0 & 7)) << 3;
    const size_t fbase = (size_t)b * DI << 10;

    float dx0, dy0, dz0, dx1, dy1, dz1, mk0, mk1;
    s16x8 fr0 = {}, fr1 = {};
    unsigned int pk[8];

    // ---- prologue: tile 0 -> buf0; then preload tile 1 regs ----
    LOAD_DM(0);
    LOAD_FEAT(0);
    COMPUTE_PHI();
    WRITE_PHI(phi0b);
    WRITE_FEAT(feat0b);
    LOAD_DM(64);
    LOAD_FEAT(64);

    // ---- main loop: iter s reads buf(s&1), writes tile s+1 -> buf(~s&1) ----
    for (int s = 0; s < 15; ++s) {
        unsigned short* rp = (s & 1) ? phi1b  : phi0b;
        unsigned short* rf = (s & 1) ? feat1b : feat0b;
        unsigned short* wp = (s & 1) ? phi0b  : phi1b;
        unsigned short* wf = (s & 1) ? feat0b : feat1b;
        __syncthreads();
        // phi(s+1) from regs loaded last iter, then stage tile s+1 into the
        // other buffer WHILE fr0/fr1 still hold tile s+1 (R8 bug: reload
        // clobbered them first -> staged tile s+2 as s+1).
        COMPUTE_PHI();
        WRITE_PHI(wp);
        WRITE_FEAT(wf);
        // NOW reissue loads for tile s+2: consumed next iter after the next
        // barrier -> a full region (GEMM1 + next phi) of latency cover.
        {
            const int mnext = (s < 14 ? (s + 2) : 15) * 64;
            LOAD_DM(mnext);
            LOAD_FEAT(mnext);
        }
        // GEMM1 on tile s (LDS) — co-scheduled with the exp2 VALU above
        GEMM1(rp, rf);
    }
    __syncthreads();
    GEMM1(phi1b, feat1b);               // tail: tile 15 lives in buf1

    __syncthreads();   // phi bufs free -> Tt may overwrite

    // ---- acc (C: col=l15=i_local, row=q*4+r=k; tiles (n_local, i-tile)) -> Tt[n][k*104+i]
#pragma unroll
    for (int rr = 0; rr < 2; ++rr) {
        int nloc = 2*wr + rr;
#pragma unroll
        for (int cc = 0; cc < 4; ++cc) {
            int i = (ct0+cc)*16 + l15;
            if (ct0 + cc < 7 && i < DI) {
#pragma unroll
                for (int r = 0; r < 4; ++r)
                    Tt[nloc*TTST + (q*4+r)*DI + i] = f2b(acc[rr][cc][r]);
            }
        }
    }
    __syncthreads();

    // ---- GEMM2: y[o,n] = sum_ki Wbf[k,o,i]*Tt[n][ki]; 52 K-steps of 32 ----
    f32x4 y0 = (f32x4){0.f,0.f,0.f,0.f}, y1 = (f32x4){0.f,0.f,0.f,0.f};
    const int o0 = wave*16 + l15;
    const int o1 = 128 + l15;            // o-tile 8, wave 0's second acc
#pragma unroll 4
    for (int s3 = 0; s3 < 52; ++s3) {
        int a = s3*4 + q;                // 8-elem ki block; k=a/13, i=(a%13)*8
        int k = a / 13;
        int i = (a - k*13) << 3;
        s16x8 bf = *(const s16x8*)(Tt + (l15 & 7)*TTST + s3*32 + q*8);
        s16x8 af = *(const s16x8*)(Wbf + (size_t)(k*DO + o0)*DI + i);
        y0 = __builtin_amdgcn_mfma_f32_16x16x32_bf16(af, bf, y0, 0, 0, 0);
        if (wave == 0) {
            s16x8 ag = *(const s16x8*)(Wbf + (size_t)(k*DO + o1)*DI + i);
            y1 = __builtin_amdgcn_mfma_f32_16x16x32_bf16(ag, bf, y1, 0, 0, 0);
        }
    }
    if (l15 < 8) {
#pragma unroll
        for (int r = 0; r < 4; ++r)
            ylds[(wave*16 + q*4 + r)*YST + l15] = y0[r];
        if (wave == 0) {
#pragma unroll
            for (int r = 0; r < 4; ++r)
                ylds[(128 + q*4 + r)*YST + l15] = y1[r];
        }
    }
    __syncthreads();

    // ---- gating epilogue: out[b, o(<120), n0+nn] fp32 ----
    const float L2E = 1.4426950408889634f;
    for (int idx = t; idx < 120*8; idx += 512) {
        int o = idx >> 3, nn = idx & 7;
        float y = ylds[o*YST + nn];
        float v;
        if (o < 32) {
            v = fmaxf(y, 0.f);
        } else if (o < 80) {
            float g = ylds[(120 + (o-32)/3)*YST + nn];
            v = y * frcp_(1.f + fexp2(-g*L2E));
        } else {
            float g = ylds[(136 + (o-80)/5)*YST + nn];
            v = y * frcp_(1.f + fexp2(-g*L2E));
        }
        out_g[((size_t)(b*120 + o) << 10) + n0 + nn] = v;
    }
}

extern "C" void kernel_launch(void* const* d_in, const int* in_sizes, int n_in,
                              void* d_out, int out_size, void* d_ws, size_t ws_size,
                              hipStream_t stream) {
    const float* feat = (const float*)d_in[0];  // [4,104,1024] fp32
    const float* diff = (const float*)d_in[1];  // [4,1024,1024,3] fp32
    const float* mask = (const float*)d_in[2];  // [4,1024,1024] fp32
    const float* W    = (const float*)d_in[3];  // [16,144,104] fp32
    float* out = (float*)d_out;                 // [4,120,1024] fp32
    unsigned short* ws = (unsigned short*)d_ws; // Wbf (479 KB) + featbf (852 KB)
    (void)in_sizes; (void)n_in; (void)out_size; (void)ws_size;
    cvt_kernel<<<dim3((W_ELEMS + F_ELEMS)/8/256), dim3(256), 0, stream>>>(feat, W, ws);
    pgb_kernel<<<dim3(512), dim3(512), 0, stream>>>(ws, diff, mask, out);
}